// Round 3
// baseline (399.629 us; speedup 1.0000x reference)
//
#include <hip/hip_runtime.h>

// Patch_Embed_Rotate: per-16x16-patch conditional transpose.
// out[b,c,hi*16+i,wi*16+j] = mask[b,wi,hi] ? x[b,c,hi*16+j,wi*16+i]
//                                          : x[b,c,hi*16+i,wi*16+j]
// B=256, C=3, H=W=224, P=16.
//
// R6 = PROBE ROUND (intentional dur_us regression, revert next round).
// R5 post-mortem: sc0/sc1 system-scope loads read STALE x (harness restores
// inputs device-side each iter; bypass loads skip the cache holding fresh
// data) -> absmax 2.3e17. Scope-bit lever dead. Reverted to plain accesses.
// R3-R4 re-read: the "poison drain" was INFERRED, never shown in WRITE_SIZE
// (which counts evict-writebacks!). If our dispatch really measured
// FETCH~78MB WRITE~154MB in 92.7us, we're at 2.5 TB/s = 40% of ceiling with
// idle pipes -> NOT traffic-bound, theory wrong. But our dispatch has been
// hidden below the top-5 cutoff (fills at 92.7-95.3us vs us ~92.5us) every
// round. This probe adds ~64us of tail s_sleep per wave: stretches our
// dispatch to ~130-160us (=> #1 in top-5) with byte counters unperturbed.
// Pre-committed read: FETCH+WRITE~308MB -> no drain, attack concurrency next;
// WRITE>=250MB -> drain real, revert+declare roofline; FETCH 78 vs 154 ->
// x L3-residency.
//
// Structure (verified correct since R3): unit = 4 consecutive patches
// (n = hi*14+wi, 49 quads per image-channel exactly). 64 lanes = 4 patches x
// 16 lanes; each lane owns a 4x4 sub-block (4 float4 regs). Patch transpose =
// ds_bpermute lane swap (lane' = 16p+4*beta+alpha) + transposed element
// indexing (register renaming): out[r].elem[e] = B[e].elem[r].

#define NPATCH 14

typedef float f4 __attribute__((ext_vector_type(4)));

__device__ __forceinline__ float bperm(int idx, float s) {
    return __int_as_float(__builtin_amdgcn_ds_bpermute(idx, __float_as_int(s)));
}

__global__ __launch_bounds__(256) void patch_rotate_kernel(
    const float* __restrict__ x,
    const int*   __restrict__ mask,
    float*       __restrict__ out)
{
    const int tid  = threadIdx.x;
    const int lane = tid & 63;
    const int wv   = tid >> 6;
    const int w    = blockIdx.x * 4 + wv;      // wave id, [0, 18816)

    const int p  = lane >> 4;                  // patch within quad, 0..3
    const int a  = (lane >> 2) & 3;            // sub-block row, 0..3
    const int bb = lane & 3;                   // sub-block col, 0..3
    const int lp = (lane & 48) | (bb << 2) | a;   // transposed partner lane
    const int idx = lp << 2;                   // bpermute byte index

    #pragma unroll
    for (int uu = 0; uu < 2; ++uu) {
        const int u   = 2 * w + uu;            // quad-unit id, [0, 37632)
        const int img = u / 49;                // b*3 + c
        const int q   = u % 49;
        const int n   = 4 * q + p;             // global patch number, 0..195
        const int hi  = n / NPATCH;
        const int wi  = n % NPATCH;
        const int b   = img / 3;

        const int row = hi * 16 + 4 * a;
        const int col = wi * 16 + 4 * bb;
        const size_t base = ((size_t)img * 224 + row) * 224 + col;

        // plain cached loads (R3 known-good path)
        const f4 v0 = *(const f4*)(x + base);
        const f4 v1 = *(const f4*)(x + base + 224);
        const f4 v2 = *(const f4*)(x + base + 448);
        const f4 v3 = *(const f4*)(x + base + 672);

        // per-patch mask (16 lanes share each address) — cached load, tiny
        const int m = mask[(b * NPATCH + wi) * NPATCH + hi];

        // gather transposed partner's 4 regs (16x ds_bpermute_b32, no LDS mem)
        f4 B0, B1, B2, B3;
        B0.x = bperm(idx, v0.x); B0.y = bperm(idx, v0.y);
        B0.z = bperm(idx, v0.z); B0.w = bperm(idx, v0.w);
        B1.x = bperm(idx, v1.x); B1.y = bperm(idx, v1.y);
        B1.z = bperm(idx, v1.z); B1.w = bperm(idx, v1.w);
        B2.x = bperm(idx, v2.x); B2.y = bperm(idx, v2.y);
        B2.z = bperm(idx, v2.z); B2.w = bperm(idx, v2.w);
        B3.x = bperm(idx, v3.x); B3.y = bperm(idx, v3.y);
        B3.z = bperm(idx, v3.z); B3.w = bperm(idx, v3.w);

        // out reg r element e = B[e].elem[r]  (4x4 in-register transpose)
        f4 r0 = v0, r1 = v1, r2 = v2, r3 = v3;
        if (m) {
            r0.x = B0.x; r0.y = B1.x; r0.z = B2.x; r0.w = B3.x;
            r1.x = B0.y; r1.y = B1.y; r1.z = B2.y; r1.w = B3.y;
            r2.x = B0.z; r2.y = B1.z; r2.z = B2.z; r2.w = B3.z;
            r3.x = B0.w; r3.y = B1.w; r3.z = B2.w; r3.w = B3.w;
        }

        *(f4*)(out + base)       = r0;
        *(f4*)(out + base + 224) = r1;
        *(f4*)(out + base + 448) = r2;
        *(f4*)(out + base + 672) = r3;
    }

    // ---- time-dilation probe: ~64us tail sleep per wave (24 x 100x64 cyc
    // @2.4GHz). No memory side effects; inflates dispatch dur past the
    // 95.3us fill cutoff so OUR counters appear in top-5. REMOVE NEXT ROUND.
    #pragma unroll
    for (int s = 0; s < 24; ++s)
        asm volatile("s_sleep 100");
}

extern "C" void kernel_launch(void* const* d_in, const int* in_sizes, int n_in,
                              void* d_out, int out_size, void* d_ws, size_t ws_size,
                              hipStream_t stream) {
    const float* x    = (const float*)d_in[0];
    const int*   mask = (const int*)d_in[1];
    float*       out  = (float*)d_out;

    // 37632 quad-units, 2 per wave, 4 waves/block -> 4704 blocks exactly.
    patch_rotate_kernel<<<4704, 256, 0, stream>>>(x, mask, out);
}

// Round 4
// 268.225 us; speedup vs baseline: 1.4899x; 1.4899x over previous
//
#include <hip/hip_runtime.h>

// Patch_Embed_Rotate: per-16x16-patch conditional transpose.
// out[b,c,hi*16+i,wi*16+j] = mask[b,wi,hi] ? x[b,c,hi*16+j,wi*16+i]
//                                          : x[b,c,hi*16+i,wi*16+j]
// B=256, C=3, H=W=224, P=16.
//
// R6 probe post-mortem (counters for OUR dispatch, sleep-dilated):
//   WRITE_SIZE = 147.0 MiB EXACTLY (= output) -> no write amplification,
//     no poison-drain. R3's drain theory is dead.
//   FETCH_SIZE = 74.3 MiB = half of x -> half the input is L3-resident.
//     True HBM floor ~221 MiB @ 6.3 TB/s ~= 35us.
//   VALUBusy ~3%, bank conflicts 0, VGPR 28.
// Un-dilated kernel: 221 MiB / 92.5us = 2.4 TB/s = 38% of achievable with
// every pipe idle -> NOT traffic-bound. Implied per-wave lifetime 10-40us
// for 16 VMEM ops = pathological. Common property of all three 92us
// kernels: tiny one-shot waves (18,816 WG launches, each wave eats a full
// loaded HBM latency at its head, then dies).
//
// R7: persistent single-shot grid. 1176 blocks x 4 waves = 4704 waves, ALL
// resident at once (<=4.6 blocks/CU; __launch_bounds__(256,8) holds VGPR
// <=64 so the 32-wave/CU cap never binds). Zero WG relaunch. Each wave owns
// 8 consecutive quad-units, processed through a 1-deep software pipeline
// (issue unit j+1's loads before processing unit j) -> no exposed HBM
// latency after the prologue. Per-unit addresses/order identical to the
// verified R3 kernel. Prediction: kernel 92.5 -> 45-60us, dur_us -> 205-220;
// null -> structure theory dead, declare environment roofline.
//
// Geometry (verified correct since R3): unit = 4 consecutive patches
// (n = 4q+p, q=u%49, 49 quads per image-channel exactly). 64 lanes =
// 4 patches x 16 lanes; each lane owns a 4x4 sub-block (4 float4 regs).
// Patch transpose = ds_bpermute lane swap (lane' = 16p+4*bb+a) + transposed
// element indexing: out[r].elem[e] = B[e].elem[r].

#define NPATCH 14

typedef float f4 __attribute__((ext_vector_type(4)));

__device__ __forceinline__ float bperm(int idx, float s) {
    return __int_as_float(__builtin_amdgcn_ds_bpermute(idx, __float_as_int(s)));
}

struct Unit {
    size_t base;
    int    m;
    f4     v0, v1, v2, v3;
};

__device__ __forceinline__ void load_unit(const float* __restrict__ x,
                                          const int*   __restrict__ mask,
                                          int u, int p, int a, int bb,
                                          Unit& U)
{
    const int img = u / 49;                 // b*3 + c
    const int q   = u - img * 49;
    const int n   = 4 * q + p;              // global patch number, 0..195
    const int hi  = n / NPATCH;
    const int wi  = n - hi * NPATCH;
    const int b   = img / 3;

    const int row = hi * 16 + 4 * a;
    const int col = wi * 16 + 4 * bb;
    U.base = ((size_t)img * 224 + row) * 224 + col;

    // per-patch mask (16 lanes share each address) — cached, tiny
    U.m = mask[(b * NPATCH + wi) * NPATCH + hi];

    U.v0 = *(const f4*)(x + U.base);
    U.v1 = *(const f4*)(x + U.base + 224);
    U.v2 = *(const f4*)(x + U.base + 448);
    U.v3 = *(const f4*)(x + U.base + 672);
}

__device__ __forceinline__ void proc_store(float* __restrict__ out,
                                           int idx, const Unit& U)
{
    const f4 v0 = U.v0, v1 = U.v1, v2 = U.v2, v3 = U.v3;

    // gather transposed partner's 4 regs (16x ds_bpermute_b32, no LDS mem)
    f4 B0, B1, B2, B3;
    B0.x = bperm(idx, v0.x); B0.y = bperm(idx, v0.y);
    B0.z = bperm(idx, v0.z); B0.w = bperm(idx, v0.w);
    B1.x = bperm(idx, v1.x); B1.y = bperm(idx, v1.y);
    B1.z = bperm(idx, v1.z); B1.w = bperm(idx, v1.w);
    B2.x = bperm(idx, v2.x); B2.y = bperm(idx, v2.y);
    B2.z = bperm(idx, v2.z); B2.w = bperm(idx, v2.w);
    B3.x = bperm(idx, v3.x); B3.y = bperm(idx, v3.y);
    B3.z = bperm(idx, v3.z); B3.w = bperm(idx, v3.w);

    // out reg r element e = B[e].elem[r]  (4x4 in-register transpose)
    f4 r0 = v0, r1 = v1, r2 = v2, r3 = v3;
    if (U.m) {
        r0.x = B0.x; r0.y = B1.x; r0.z = B2.x; r0.w = B3.x;
        r1.x = B0.y; r1.y = B1.y; r1.z = B2.y; r1.w = B3.y;
        r2.x = B0.z; r2.y = B1.z; r2.z = B2.z; r2.w = B3.z;
        r3.x = B0.w; r3.y = B1.w; r3.z = B2.w; r3.w = B3.w;
    }

    *(f4*)(out + U.base)       = r0;
    *(f4*)(out + U.base + 224) = r1;
    *(f4*)(out + U.base + 448) = r2;
    *(f4*)(out + U.base + 672) = r3;
}

__global__ __launch_bounds__(256, 8) void patch_rotate_kernel(
    const float* __restrict__ x,
    const int*   __restrict__ mask,
    float*       __restrict__ out)
{
    const int tid  = threadIdx.x;
    const int lane = tid & 63;
    const int wv   = tid >> 6;
    const int wave = blockIdx.x * 4 + wv;   // [0, 4704)
    const int u0   = wave * 8;              // 8 consecutive units per wave

    const int p  = lane >> 4;               // patch within quad, 0..3
    const int a  = (lane >> 2) & 3;         // sub-block row, 0..3
    const int bb = lane & 3;                // sub-block col, 0..3
    const int idx = ((lane & 48) | (bb << 2) | a) << 2;  // bpermute byte idx

    // 1-deep software pipeline over 8 units: loads for j+1 are issued
    // before unit j is consumed, so post-prologue no full-latency stall.
    // All indexing static (full unroll, named cur/nxt) — rule #20.
    Unit cur, nxt;
    load_unit(x, mask, u0, p, a, bb, cur);

    #pragma unroll
    for (int j = 0; j < 8; ++j) {
        if (j < 7) load_unit(x, mask, u0 + j + 1, p, a, bb, nxt);
        proc_store(out, idx, cur);
        if (j < 7) cur = nxt;
    }
}

extern "C" void kernel_launch(void* const* d_in, const int* in_sizes, int n_in,
                              void* d_out, int out_size, void* d_ws, size_t ws_size,
                              hipStream_t stream) {
    const float* x    = (const float*)d_in[0];
    const int*   mask = (const int*)d_in[1];
    float*       out  = (float*)d_out;

    // 4704 waves x 8 units = 37632 units exactly; 1176 blocks x 4 waves,
    // single-shot (all waves resident), zero relaunch.
    patch_rotate_kernel<<<1176, 256, 0, stream>>>(x, mask, out);
}